// Round 1
// baseline (163.912 us; speedup 1.0000x reference)
//
#include <hip/hip_runtime.h>
#include <hip/hip_fp16.h>
#include <cstdint>
#include <cstddef>

using f16x8 = _Float16 __attribute__((ext_vector_type(8)));
using f16x4 = _Float16 __attribute__((ext_vector_type(4)));
using f32x4 = float __attribute__((ext_vector_type(4)));

#define GLDS16(g, l) __builtin_amdgcn_global_load_lds(                        \
    (const __attribute__((address_space(1))) void*)(g),                       \
    (__attribute__((address_space(3))) void*)(l), 16, 0, 0)

// ---------------------------------------------------------------- cast f32->f16
__global__ void cast_f32_f16(const float* __restrict__ in,
                             _Float16* __restrict__ out, int n4) {
  int i = blockIdx.x * blockDim.x + threadIdx.x;
  if (i >= n4) return;
  float4 v = reinterpret_cast<const float4*>(in)[i];
  f16x4 h;
  h[0] = (_Float16)v.x; h[1] = (_Float16)v.y;
  h[2] = (_Float16)v.z; h[3] = (_Float16)v.w;
  reinterpret_cast<f16x4*>(out)[i] = h;
}

// ---------------------------------------------------------------- GEMM  C = A * B^T + bias
// A: M x K (f16, row-major), B: N x K (f16, row-major), C: M x N (TOUT)
// 128x128 tile, BK=32, 256 threads = 4 waves, each wave 64x64 (4x4 mfma 16x16x32)
template <typename TOUT>
__global__ __launch_bounds__(256) void gemm_bt(
    const _Float16* __restrict__ A, const _Float16* __restrict__ B,
    const float* __restrict__ bias, TOUT* __restrict__ C,
    int M, int N, int K) {
  __shared__ _Float16 As[128 * 32];
  __shared__ _Float16 Bs[128 * 32];

  const int tid  = threadIdx.x;
  const int lane = tid & 63;
  const int wave = tid >> 6;
  const int l15  = lane & 15;
  const int quad = lane >> 4;
  const int m0 = blockIdx.y * 128;
  const int n0 = blockIdx.x * 128;
  const int wr = (wave >> 1) * 64;   // wave row offset in tile
  const int wc = (wave & 1) * 64;    // wave col offset in tile

  // staging: chunk c = issue*256 + tid ; row = c>>2 (0..127), k-chunk = (c&3)*8
  const int srow = tid >> 2;
  const int skc  = (tid & 3) * 8;
  const _Float16* Ag0 = A + (size_t)(m0 + srow) * K + skc;
  const _Float16* Ag1 = A + (size_t)(m0 + 64 + srow) * K + skc;
  const _Float16* Bg0 = B + (size_t)(n0 + srow) * K + skc;
  const _Float16* Bg1 = B + (size_t)(n0 + 64 + srow) * K + skc;
  _Float16* Asd0 = &As[tid * 8];
  _Float16* Asd1 = &As[(256 + tid) * 8];
  _Float16* Bsd0 = &Bs[tid * 8];
  _Float16* Bsd1 = &Bs[(256 + tid) * 8];

  f32x4 acc[4][4];
#pragma unroll
  for (int i = 0; i < 4; i++)
#pragma unroll
    for (int j = 0; j < 4; j++) acc[i][j] = f32x4{0.f, 0.f, 0.f, 0.f};

  for (int kt = 0; kt < K; kt += 32) {
    __syncthreads();
    GLDS16(Ag0 + kt, Asd0);
    GLDS16(Ag1 + kt, Asd1);
    GLDS16(Bg0 + kt, Bsd0);
    GLDS16(Bg1 + kt, Bsd1);
    __syncthreads();

    f16x8 af[4], bf[4];
#pragma unroll
    for (int mi = 0; mi < 4; mi++)
      af[mi] = *reinterpret_cast<const f16x8*>(&As[(wr + mi * 16 + l15) * 32 + quad * 8]);
#pragma unroll
    for (int ni = 0; ni < 4; ni++)
      bf[ni] = *reinterpret_cast<const f16x8*>(&Bs[(wc + ni * 16 + l15) * 32 + quad * 8]);
#pragma unroll
    for (int mi = 0; mi < 4; mi++)
#pragma unroll
      for (int ni = 0; ni < 4; ni++)
        acc[mi][ni] = __builtin_amdgcn_mfma_f32_16x16x32_f16(af[mi], bf[ni], acc[mi][ni], 0, 0, 0);
  }

  // epilogue: C/D layout row = quad*4 + r, col = l15
#pragma unroll
  for (int mi = 0; mi < 4; mi++) {
    const int row = m0 + wr + mi * 16 + quad * 4;
#pragma unroll
    for (int ni = 0; ni < 4; ni++) {
      const int col = n0 + wc + ni * 16 + l15;
      const float bv = bias ? bias[col] : 0.f;
#pragma unroll
      for (int r = 0; r < 4; r++) {
        float v = acc[mi][ni][r] + bv;
        C[(size_t)(row + r) * N + col] = (TOUT)v;
      }
    }
  }
}

// ---------------------------------------------------------------- windowed attention
// qkv: (2*T, 3072) f16 : cols [0,1024)=q, [1024,2048)=k, [2048,3072)=v ; per-head 64 dims
// o:   (2*T, 1024) f16
// block = (n, h, qtile of 64 queries); 4 waves x 16 queries; window = 192 key rows
#define T_LEN 1024
#define KSTR 72    // Kw row stride (elements), pad 64->72 (2-way banks, 16B aligned)
#define VSTR 200   // Vt / P row stride, pad 192->200

__global__ __launch_bounds__(256) void attn_win(
    const _Float16* __restrict__ qkv, _Float16* __restrict__ o) {
  __shared__ _Float16 KP[192 * KSTR];  // K window [j][d]; later reused as P (4*16*VSTR <= 192*KSTR)
  __shared__ _Float16 Vt[64 * VSTR];   // V window transposed [d][j]

  const int b  = blockIdx.x;
  const int qt = b & 15;
  const int h  = (b >> 4) & 15;
  const int n  = b >> 8;
  const int t0 = qt * 64;

  const int tid  = threadIdx.x;
  const int lane = tid & 63;
  const int wave = tid >> 6;
  const int l15  = lane & 15;
  const int quad = lane >> 4;

  const size_t rowstr = 3072;
  const _Float16* qbase = qkv + (size_t)n * T_LEN * rowstr + h * 64;
  const _Float16* kbase = qbase + 1024;
  const _Float16* vbase = qbase + 2048;

  // ---- stage K window [192][64] and V^T [64][192] (zero-fill out-of-range rows)
  for (int idx = tid; idx < 192 * 8; idx += 256) {
    const int j  = idx >> 3;
    const int d8 = (idx & 7) * 8;
    const int t  = t0 - 64 + j;
    f16x8 kv, vv;
    if (t >= 0 && t < T_LEN) {
      kv = *reinterpret_cast<const f16x8*>(kbase + (size_t)t * rowstr + d8);
      vv = *reinterpret_cast<const f16x8*>(vbase + (size_t)t * rowstr + d8);
    } else {
      for (int i = 0; i < 8; i++) { kv[i] = (_Float16)0.f; vv[i] = (_Float16)0.f; }
    }
    *reinterpret_cast<f16x8*>(&KP[j * KSTR + d8]) = kv;
#pragma unroll
    for (int i = 0; i < 8; i++) Vt[(d8 + i) * VSTR + j] = vv[i];
  }
  __syncthreads();

  // ---- Q fragments (A-layout: m=l15 -> query, k=quad*8+i) straight from global
  const _Float16* qrow = qbase + (size_t)(t0 + wave * 16 + l15) * rowstr;
  const f16x8 qf0 = *reinterpret_cast<const f16x8*>(qrow + quad * 8);
  const f16x8 qf1 = *reinterpret_cast<const f16x8*>(qrow + 32 + quad * 8);

  // ---- S = Q K^T : 16x192 per wave = 12 tiles x 2 k-steps
  f32x4 accs[12];
#pragma unroll
  for (int jt = 0; jt < 12; jt++) accs[jt] = f32x4{0.f, 0.f, 0.f, 0.f};
#pragma unroll
  for (int jt = 0; jt < 12; jt++) {
    const f16x8 b0 = *reinterpret_cast<const f16x8*>(&KP[(jt * 16 + l15) * KSTR + quad * 8]);
    const f16x8 b1 = *reinterpret_cast<const f16x8*>(&KP[(jt * 16 + l15) * KSTR + 32 + quad * 8]);
    accs[jt] = __builtin_amdgcn_mfma_f32_16x16x32_f16(qf0, b0, accs[jt], 0, 0, 0);
    accs[jt] = __builtin_amdgcn_mfma_f32_16x16x32_f16(qf1, b1, accs[jt], 0, 0, 0);
  }
  __syncthreads();  // all waves done reading KP; it becomes P storage below

  // ---- mask + softmax (C layout: row q_local = quad*4+r, col j = jt*16+l15)
  float rmax[4] = {-1e30f, -1e30f, -1e30f, -1e30f};
#pragma unroll
  for (int jt = 0; jt < 12; jt++) {
    const int jcol = jt * 16 + l15;
    const int tabs = t0 - 64 + jcol;
#pragma unroll
    for (int r = 0; r < 4; r++) {
      const int q = wave * 16 + quad * 4 + r;  // query index in 64-tile
      const bool valid = (jcol >= q) && (jcol <= q + 128) && (tabs >= 0) && (tabs < T_LEN);
      const float s = valid ? accs[jt][r] * 0.125f : -1e30f;
      accs[jt][r] = s;
      rmax[r] = fmaxf(rmax[r], s);
    }
  }
#pragma unroll
  for (int r = 0; r < 4; r++)
#pragma unroll
    for (int m = 1; m < 16; m <<= 1) rmax[r] = fmaxf(rmax[r], __shfl_xor(rmax[r], m));

  float rsum[4] = {0.f, 0.f, 0.f, 0.f};
#pragma unroll
  for (int jt = 0; jt < 12; jt++)
#pragma unroll
    for (int r = 0; r < 4; r++) {
      const float p = __expf(accs[jt][r] - rmax[r]);
      accs[jt][r] = p;
      rsum[r] += p;
    }
#pragma unroll
  for (int r = 0; r < 4; r++)
#pragma unroll
    for (int m = 1; m < 16; m <<= 1) rsum[r] += __shfl_xor(rsum[r], m);

  // ---- write P (f16) to per-wave LDS region: C-layout -> A-layout transform
  _Float16* Pw = &KP[wave * 16 * VSTR];
#pragma unroll
  for (int jt = 0; jt < 12; jt++)
#pragma unroll
    for (int r = 0; r < 4; r++)
      Pw[(quad * 4 + r) * VSTR + jt * 16 + l15] = (_Float16)accs[jt][r];
  __syncthreads();

  // ---- O = P V : 16x64 per wave = 4 tiles x 6 k-steps
  f32x4 acco[4];
#pragma unroll
  for (int ni = 0; ni < 4; ni++) acco[ni] = f32x4{0.f, 0.f, 0.f, 0.f};
#pragma unroll
  for (int ks = 0; ks < 6; ks++) {
    const f16x8 pa = *reinterpret_cast<const f16x8*>(&Pw[l15 * VSTR + ks * 32 + quad * 8]);
#pragma unroll
    for (int ni = 0; ni < 4; ni++) {
      const f16x8 vb = *reinterpret_cast<const f16x8*>(&Vt[(ni * 16 + l15) * VSTR + ks * 32 + quad * 8]);
      acco[ni] = __builtin_amdgcn_mfma_f32_16x16x32_f16(pa, vb, acco[ni], 0, 0, 0);
    }
  }

  float rinv[4];
#pragma unroll
  for (int r = 0; r < 4; r++) rinv[r] = 1.f / rsum[r];

  _Float16* obase = o + (size_t)(n * T_LEN + t0 + wave * 16) * 1024 + h * 64;
#pragma unroll
  for (int ni = 0; ni < 4; ni++)
#pragma unroll
    for (int r = 0; r < 4; r++)
      obase[(size_t)(quad * 4 + r) * 1024 + ni * 16 + l15] = (_Float16)(acco[ni][r] * rinv[r]);
}

// ---------------------------------------------------------------- launch
extern "C" void kernel_launch(void* const* d_in, const int* in_sizes, int n_in,
                              void* d_out, int out_size, void* d_ws, size_t ws_size,
                              hipStream_t stream) {
  const float* x   = (const float*)d_in[0];
  const float* w_q = (const float*)d_in[1];
  const float* b_q = (const float*)d_in[2];
  const float* w_k = (const float*)d_in[3];
  const float* b_k = (const float*)d_in[4];
  const float* w_v = (const float*)d_in[5];
  const float* b_v = (const float*)d_in[6];
  const float* w_o = (const float*)d_in[7];
  const float* b_o = (const float*)d_in[8];
  float* out = (float*)d_out;

  char* ws = (char*)d_ws;
  _Float16* xh   = (_Float16*)(ws);                      // 2M el (4MB) ; reused as oh after QKV gemm
  _Float16* wcat = (_Float16*)(ws + (4ull << 20));       // 3M el (6MB): [w_q; w_k; w_v] rows
  _Float16* woh  = (_Float16*)(ws + (10ull << 20));      // 1M el (2MB)
  _Float16* qkvh = (_Float16*)(ws + (12ull << 20));      // 6M el (12MB): (2048, 3072)
  _Float16* oh   = xh;                                   // alias: x dead after QKV gemm
  float*    bcat = (float*)(ws + (24ull << 20));         // 3072 f32

  const int MEL = 2 * 1024 * 1024;  // x elements
  const int WEL = 1024 * 1024;      // weight elements

  cast_f32_f16<<<MEL / 4 / 256, 256, 0, stream>>>(x, xh, MEL / 4);
  cast_f32_f16<<<WEL / 4 / 256, 256, 0, stream>>>(w_q, wcat, WEL / 4);
  cast_f32_f16<<<WEL / 4 / 256, 256, 0, stream>>>(w_k, wcat + WEL, WEL / 4);
  cast_f32_f16<<<WEL / 4 / 256, 256, 0, stream>>>(w_v, wcat + 2 * WEL, WEL / 4);
  cast_f32_f16<<<WEL / 4 / 256, 256, 0, stream>>>(w_o, woh, WEL / 4);
  hipMemcpyAsync(bcat,        b_q, 1024 * sizeof(float), hipMemcpyDeviceToDevice, stream);
  hipMemcpyAsync(bcat + 1024, b_k, 1024 * sizeof(float), hipMemcpyDeviceToDevice, stream);
  hipMemcpyAsync(bcat + 2048, b_v, 1024 * sizeof(float), hipMemcpyDeviceToDevice, stream);

  // fused QKV projection: (2048 x 1024) * (3072 x 1024)^T -> (2048 x 3072) f16
  gemm_bt<_Float16><<<dim3(24, 16), 256, 0, stream>>>(xh, wcat, bcat, qkvh, 2048, 3072, 1024);

  // windowed attention -> oh (2048 x 1024) f16
  attn_win<<<512, 256, 0, stream>>>(qkvh, oh);

  // output projection: (2048 x 1024) * (1024 x 1024)^T -> (2048 x 1024) f32
  gemm_bt<float><<<dim3(8, 16), 256, 0, stream>>>(oh, woh, b_o, out, 2048, 1024, 1024);
}

// Round 2
// 146.983 us; speedup vs baseline: 1.1152x; 1.1152x over previous
//
#include <hip/hip_runtime.h>
#include <hip/hip_fp16.h>
#include <cstdint>
#include <cstddef>

using f16x8 = _Float16 __attribute__((ext_vector_type(8)));
using f16x4 = _Float16 __attribute__((ext_vector_type(4)));
using f32x4 = float __attribute__((ext_vector_type(4)));

#define GLDS16(g, l) __builtin_amdgcn_global_load_lds(                        \
    (const __attribute__((address_space(1))) void*)(g),                       \
    (__attribute__((address_space(3))) void*)(l), 16, 0, 0)

// ---------------------------------------------------------------- fused prep
// One dispatch: cast x + 4 weights f32->f16, concat 3 biases. All segment
// boundaries are multiples of 256 float4-units except the bias tail, so every
// wave is branch-uniform.
__device__ inline void cast4(const float* __restrict__ in,
                             _Float16* __restrict__ out, int i) {
  float4 v = reinterpret_cast<const float4*>(in)[i];
  f16x4 h;
  h[0] = (_Float16)v.x; h[1] = (_Float16)v.y;
  h[2] = (_Float16)v.z; h[3] = (_Float16)v.w;
  reinterpret_cast<f16x4*>(out)[i] = h;
}

__global__ void prep_kernel(const float* __restrict__ x,
                            const float* __restrict__ wq, const float* __restrict__ wk,
                            const float* __restrict__ wv, const float* __restrict__ wo,
                            const float* __restrict__ bq, const float* __restrict__ bk,
                            const float* __restrict__ bv,
                            _Float16* __restrict__ xh, _Float16* __restrict__ wcat,
                            _Float16* __restrict__ woh, float* __restrict__ bcat) {
  int i = blockIdx.x * blockDim.x + threadIdx.x;
  const int XU = 512 * 1024;  // x: 2M floats = 512K float4
  const int WU = 256 * 1024;  // each weight: 1M floats = 256K float4
  if (i < XU) { cast4(x, xh, i); return; }
  i -= XU;
  if (i < WU) { cast4(wq, wcat, i); return; }
  i -= WU;
  if (i < WU) { cast4(wk, wcat + 1024 * 1024, i); return; }
  i -= WU;
  if (i < WU) { cast4(wv, wcat + 2 * 1024 * 1024, i); return; }
  i -= WU;
  if (i < WU) { cast4(wo, woh, i); return; }
  i -= WU;
  if (i < 256) { reinterpret_cast<float4*>(bcat)[i] = reinterpret_cast<const float4*>(bq)[i]; return; }
  i -= 256;
  if (i < 256) { reinterpret_cast<float4*>(bcat + 1024)[i] = reinterpret_cast<const float4*>(bk)[i]; return; }
  i -= 256;
  if (i < 256) { reinterpret_cast<float4*>(bcat + 2048)[i] = reinterpret_cast<const float4*>(bv)[i]; return; }
}

// ---------------------------------------------------------------- GEMM  C = A * B^T + bias
// A: M x K (f16, row-major), B: N x K (f16, row-major), C: M x N (TOUT)
// BM x 128 tile, BK=32, 256 threads = 4 waves.
// BM=128: each wave 64x64 (4x4 mfma tiles). BM=64: each wave 32x64 (2x4) —
// used for the out-projection so grid = 256 blocks (full CU coverage) instead of 128.
template <int BM, typename TOUT>
__global__ __launch_bounds__(256) void gemm_bt(
    const _Float16* __restrict__ A, const _Float16* __restrict__ B,
    const float* __restrict__ bias, TOUT* __restrict__ C,
    int M, int N, int K) {
  constexpr int WM = BM / 2;   // rows per wave
  constexpr int MI = WM / 16;  // mfma row-tiles per wave
  __shared__ _Float16 As[BM * 32];
  __shared__ _Float16 Bs[128 * 32];

  const int tid  = threadIdx.x;
  const int lane = tid & 63;
  const int wave = tid >> 6;
  const int l15  = lane & 15;
  const int quad = lane >> 4;
  const int m0 = blockIdx.y * BM;
  const int n0 = blockIdx.x * 128;
  const int wr = (wave >> 1) * WM;
  const int wc = (wave & 1) * 64;

  // staging: chunk c = issue*256 + tid ; row = c>>2, k-chunk = (c&3)*8
  const int srow = tid >> 2;
  const int skc  = (tid & 3) * 8;
  const _Float16* Ag0 = A + (size_t)(m0 + srow) * K + skc;
  const _Float16* Ag1 = A + (size_t)(m0 + 64 + srow) * K + skc;  // BM==128 only
  const _Float16* Bg0 = B + (size_t)(n0 + srow) * K + skc;
  const _Float16* Bg1 = B + (size_t)(n0 + 64 + srow) * K + skc;
  _Float16* Asd0 = &As[tid * 8];
  _Float16* Asd1 = &As[(256 + tid) * 8];
  _Float16* Bsd0 = &Bs[tid * 8];
  _Float16* Bsd1 = &Bs[(256 + tid) * 8];

  f32x4 acc[MI][4];
#pragma unroll
  for (int i = 0; i < MI; i++)
#pragma unroll
    for (int j = 0; j < 4; j++) acc[i][j] = f32x4{0.f, 0.f, 0.f, 0.f};

  for (int kt = 0; kt < K; kt += 32) {
    __syncthreads();
    GLDS16(Ag0 + kt, Asd0);
    if constexpr (BM == 128) GLDS16(Ag1 + kt, Asd1);
    GLDS16(Bg0 + kt, Bsd0);
    GLDS16(Bg1 + kt, Bsd1);
    __syncthreads();

    f16x8 af[MI], bf[4];
#pragma unroll
    for (int mi = 0; mi < MI; mi++)
      af[mi] = *reinterpret_cast<const f16x8*>(&As[(wr + mi * 16 + l15) * 32 + quad * 8]);
#pragma unroll
    for (int ni = 0; ni < 4; ni++)
      bf[ni] = *reinterpret_cast<const f16x8*>(&Bs[(wc + ni * 16 + l15) * 32 + quad * 8]);
#pragma unroll
    for (int mi = 0; mi < MI; mi++)
#pragma unroll
      for (int ni = 0; ni < 4; ni++)
        acc[mi][ni] = __builtin_amdgcn_mfma_f32_16x16x32_f16(af[mi], bf[ni], acc[mi][ni], 0, 0, 0);
  }

  // epilogue: C/D layout row = quad*4 + r, col = l15
#pragma unroll
  for (int mi = 0; mi < MI; mi++) {
    const int row = m0 + wr + mi * 16 + quad * 4;
#pragma unroll
    for (int ni = 0; ni < 4; ni++) {
      const int col = n0 + wc + ni * 16 + l15;
      const float bv = bias ? bias[col] : 0.f;
#pragma unroll
      for (int r = 0; r < 4; r++) {
        float v = acc[mi][ni][r] + bv;
        C[(size_t)(row + r) * N + col] = (TOUT)v;
      }
    }
  }
}

// ---------------------------------------------------------------- windowed attention
// qkv: (2*T, 3072) f16 : cols [0,1024)=q, [1024,2048)=k, [2048,3072)=v ; per-head 64 dims
// o:   (2*T, 1024) f16
// block = (n, h, qtile of 64 queries); 4 waves x 16 queries; window = 192 key rows
#define T_LEN 1024
#define KSTR 72    // Kw row stride (elements), pad 64->72
#define VSTR 200   // Vt / P row stride, pad 192->200

__global__ __launch_bounds__(256) void attn_win(
    const _Float16* __restrict__ qkv, _Float16* __restrict__ o) {
  __shared__ _Float16 KP[192 * KSTR];  // K window [j][d]; later reused as P
  __shared__ _Float16 Vt[64 * VSTR];   // V window transposed [d][j]

  const int b  = blockIdx.x;
  const int qt = b & 15;
  const int h  = (b >> 4) & 15;
  const int n  = b >> 8;
  const int t0 = qt * 64;

  const int tid  = threadIdx.x;
  const int lane = tid & 63;
  const int wave = tid >> 6;
  const int l15  = lane & 15;
  const int quad = lane >> 4;

  const size_t rowstr = 3072;
  const _Float16* qbase = qkv + (size_t)n * T_LEN * rowstr + h * 64;
  const _Float16* kbase = qbase + 1024;
  const _Float16* vbase = qbase + 2048;

  // ---- stage K window [192][64]: vector writes, 8 lanes per row (coalesced reads)
  for (int idx = tid; idx < 192 * 8; idx += 256) {
    const int j  = idx >> 3;
    const int d8 = (idx & 7) * 8;
    const int t  = t0 - 64 + j;
    f16x8 kv;
    if (t >= 0 && t < T_LEN) {
      kv = *reinterpret_cast<const f16x8*>(kbase + (size_t)t * rowstr + d8);
    } else {
      for (int i = 0; i < 8; i++) kv[i] = (_Float16)0.f;
    }
    *reinterpret_cast<f16x8*>(&KP[j * KSTR + d8]) = kv;
  }
  // ---- stage V^T [64][192]: consecutive lanes take consecutive j at fixed d-group,
  // so the 8 scalar LDS writes per item are lane-contiguous (2 lanes/bank = free).
  for (int it = 0; it < 6; it++) {
    const int item = it * 256 + tid;
    const int j    = (item & 63) + ((item >> 9) << 6);  // item%64 + 64*(item/512)
    const int dgrp = (item >> 6) & 7;
    const int t = t0 - 64 + j;
    f16x8 vv;
    if (t >= 0 && t < T_LEN) {
      vv = *reinterpret_cast<const f16x8*>(vbase + (size_t)t * rowstr + dgrp * 8);
    } else {
      for (int i = 0; i < 8; i++) vv[i] = (_Float16)0.f;
    }
#pragma unroll
    for (int i = 0; i < 8; i++) Vt[(dgrp * 8 + i) * VSTR + j] = vv[i];
  }
  __syncthreads();

  // ---- Q fragments (A-layout: m=l15 -> query, k=quad*8+i) straight from global
  const _Float16* qrow = qbase + (size_t)(t0 + wave * 16 + l15) * rowstr;
  const f16x8 qf0 = *reinterpret_cast<const f16x8*>(qrow + quad * 8);
  const f16x8 qf1 = *reinterpret_cast<const f16x8*>(qrow + 32 + quad * 8);

  // ---- S = Q K^T : 16x192 per wave = 12 tiles x 2 k-steps
  f32x4 accs[12];
#pragma unroll
  for (int jt = 0; jt < 12; jt++) accs[jt] = f32x4{0.f, 0.f, 0.f, 0.f};
#pragma unroll
  for (int jt = 0; jt < 12; jt++) {
    const f16x8 b0 = *reinterpret_cast<const f16x8*>(&KP[(jt * 16 + l15) * KSTR + quad * 8]);
    const f16x8 b1 = *reinterpret_cast<const f16x8*>(&KP[(jt * 16 + l15) * KSTR + 32 + quad * 8]);
    accs[jt] = __builtin_amdgcn_mfma_f32_16x16x32_f16(qf0, b0, accs[jt], 0, 0, 0);
    accs[jt] = __builtin_amdgcn_mfma_f32_16x16x32_f16(qf1, b1, accs[jt], 0, 0, 0);
  }
  __syncthreads();  // all waves done reading KP; it becomes P storage below

  // ---- mask + softmax (C layout: row q_local = quad*4+r, col j = jt*16+l15)
  float rmax[4] = {-1e30f, -1e30f, -1e30f, -1e30f};
#pragma unroll
  for (int jt = 0; jt < 12; jt++) {
    const int jcol = jt * 16 + l15;
    const int tabs = t0 - 64 + jcol;
#pragma unroll
    for (int r = 0; r < 4; r++) {
      const int q = wave * 16 + quad * 4 + r;  // query index in 64-tile
      const bool valid = (jcol >= q) && (jcol <= q + 128) && (tabs >= 0) && (tabs < T_LEN);
      const float s = valid ? accs[jt][r] * 0.125f : -1e30f;
      accs[jt][r] = s;
      rmax[r] = fmaxf(rmax[r], s);
    }
  }
#pragma unroll
  for (int r = 0; r < 4; r++)
#pragma unroll
    for (int m = 1; m < 16; m <<= 1) rmax[r] = fmaxf(rmax[r], __shfl_xor(rmax[r], m));

  float rsum[4] = {0.f, 0.f, 0.f, 0.f};
#pragma unroll
  for (int jt = 0; jt < 12; jt++)
#pragma unroll
    for (int r = 0; r < 4; r++) {
      const float p = __expf(accs[jt][r] - rmax[r]);
      accs[jt][r] = p;
      rsum[r] += p;
    }
#pragma unroll
  for (int r = 0; r < 4; r++)
#pragma unroll
    for (int m = 1; m < 16; m <<= 1) rsum[r] += __shfl_xor(rsum[r], m);

  // ---- write P (f16) to per-wave LDS region: C-layout -> A-layout transform
  _Float16* Pw = &KP[wave * 16 * VSTR];
#pragma unroll
  for (int jt = 0; jt < 12; jt++)
#pragma unroll
    for (int r = 0; r < 4; r++)
      Pw[(quad * 4 + r) * VSTR + jt * 16 + l15] = (_Float16)accs[jt][r];
  __syncthreads();

  // ---- O = P V : 16x64 per wave = 4 tiles x 6 k-steps
  f32x4 acco[4];
#pragma unroll
  for (int ni = 0; ni < 4; ni++) acco[ni] = f32x4{0.f, 0.f, 0.f, 0.f};
#pragma unroll
  for (int ks = 0; ks < 6; ks++) {
    const f16x8 pa = *reinterpret_cast<const f16x8*>(&Pw[l15 * VSTR + ks * 32 + quad * 8]);
#pragma unroll
    for (int ni = 0; ni < 4; ni++) {
      const f16x8 vb = *reinterpret_cast<const f16x8*>(&Vt[(ni * 16 + l15) * VSTR + ks * 32 + quad * 8]);
      acco[ni] = __builtin_amdgcn_mfma_f32_16x16x32_f16(pa, vb, acco[ni], 0, 0, 0);
    }
  }

  float rinv[4];
#pragma unroll
  for (int r = 0; r < 4; r++) rinv[r] = 1.f / rsum[r];

  _Float16* obase = o + (size_t)(n * T_LEN + t0 + wave * 16) * 1024 + h * 64;
#pragma unroll
  for (int ni = 0; ni < 4; ni++)
#pragma unroll
    for (int r = 0; r < 4; r++)
      obase[(size_t)(quad * 4 + r) * 1024 + ni * 16 + l15] = (_Float16)(acco[ni][r] * rinv[r]);
}

// ---------------------------------------------------------------- launch
extern "C" void kernel_launch(void* const* d_in, const int* in_sizes, int n_in,
                              void* d_out, int out_size, void* d_ws, size_t ws_size,
                              hipStream_t stream) {
  const float* x   = (const float*)d_in[0];
  const float* w_q = (const float*)d_in[1];
  const float* b_q = (const float*)d_in[2];
  const float* w_k = (const float*)d_in[3];
  const float* b_k = (const float*)d_in[4];
  const float* w_v = (const float*)d_in[5];
  const float* b_v = (const float*)d_in[6];
  const float* w_o = (const float*)d_in[7];
  const float* b_o = (const float*)d_in[8];
  float* out = (float*)d_out;

  char* ws = (char*)d_ws;
  _Float16* xh   = (_Float16*)(ws);                      // 2M el (4MB); reused as oh
  _Float16* wcat = (_Float16*)(ws + (4ull << 20));       // 3M el (6MB): [w_q; w_k; w_v]
  _Float16* woh  = (_Float16*)(ws + (10ull << 20));      // 1M el (2MB)
  _Float16* qkvh = (_Float16*)(ws + (12ull << 20));      // 6M el (12MB): (2048, 3072)
  _Float16* oh   = xh;                                   // alias: x dead after QKV gemm
  float*    bcat = (float*)(ws + (24ull << 20));         // 3072 f32

  // fused prep: 512K + 4*256K + 3*256 float4-units
  const int PREP_UNITS = 512 * 1024 + 4 * 256 * 1024 + 3 * 256;
  prep_kernel<<<(PREP_UNITS + 255) / 256, 256, 0, stream>>>(
      x, w_q, w_k, w_v, w_o, b_q, b_k, b_v, xh, wcat, woh, bcat);

  // fused QKV projection: (2048 x 1024) * (3072 x 1024)^T -> (2048 x 3072) f16
  gemm_bt<128, _Float16><<<dim3(24, 16), 256, 0, stream>>>(xh, wcat, bcat, qkvh, 2048, 3072, 1024);

  // windowed attention -> oh (2048 x 1024) f16
  attn_win<<<512, 256, 0, stream>>>(qkvh, oh);

  // output projection: (2048 x 1024) * (1024 x 1024)^T -> (2048 x 1024) f32
  // BM=64 tiles: grid 8x32 = 256 blocks (one per CU) instead of 128.
  gemm_bt<64, float><<<dim3(8, 32), 256, 0, stream>>>(oh, woh, b_o, out, 2048, 1024, 1024);
}

// Round 3
// 146.943 us; speedup vs baseline: 1.1155x; 1.0003x over previous
//
#include <hip/hip_runtime.h>
#include <hip/hip_fp16.h>
#include <cstdint>
#include <cstddef>

using f16x8 = _Float16 __attribute__((ext_vector_type(8)));
using f16x4 = _Float16 __attribute__((ext_vector_type(4)));
using f32x4 = float __attribute__((ext_vector_type(4)));

#define GLDS16(g, l) __builtin_amdgcn_global_load_lds(                        \
    (const __attribute__((address_space(1))) void*)(g),                       \
    (__attribute__((address_space(3))) void*)(l), 16, 0, 0)

// ---------------------------------------------------------------- fused prep
__device__ inline void cast4(const float* __restrict__ in,
                             _Float16* __restrict__ out, int i) {
  float4 v = reinterpret_cast<const float4*>(in)[i];
  f16x4 h;
  h[0] = (_Float16)v.x; h[1] = (_Float16)v.y;
  h[2] = (_Float16)v.z; h[3] = (_Float16)v.w;
  reinterpret_cast<f16x4*>(out)[i] = h;
}

__global__ void prep_kernel(const float* __restrict__ x,
                            const float* __restrict__ wq, const float* __restrict__ wk,
                            const float* __restrict__ wv, const float* __restrict__ wo,
                            const float* __restrict__ bq, const float* __restrict__ bk,
                            const float* __restrict__ bv,
                            _Float16* __restrict__ xh, _Float16* __restrict__ wcat,
                            _Float16* __restrict__ woh, float* __restrict__ bcat) {
  int i = blockIdx.x * blockDim.x + threadIdx.x;
  const int XU = 512 * 1024;  // x: 2M floats = 512K float4
  const int WU = 256 * 1024;  // each weight: 1M floats = 256K float4
  if (i < XU) { cast4(x, xh, i); return; }
  i -= XU;
  if (i < WU) { cast4(wq, wcat, i); return; }
  i -= WU;
  if (i < WU) { cast4(wk, wcat + 1024 * 1024, i); return; }
  i -= WU;
  if (i < WU) { cast4(wv, wcat + 2 * 1024 * 1024, i); return; }
  i -= WU;
  if (i < WU) { cast4(wo, woh, i); return; }
  i -= WU;
  if (i < 256) { reinterpret_cast<float4*>(bcat)[i] = reinterpret_cast<const float4*>(bq)[i]; return; }
  i -= 256;
  if (i < 256) { reinterpret_cast<float4*>(bcat + 1024)[i] = reinterpret_cast<const float4*>(bk)[i]; return; }
  i -= 256;
  if (i < 256) { reinterpret_cast<float4*>(bcat + 2048)[i] = reinterpret_cast<const float4*>(bv)[i]; return; }
}

// ---------------------------------------------------------------- GEMM  C = A * B^T + bias
// A: M x K (f16, row-major), B: N x K (f16, row-major), C: M x N (TOUT)
// BM x 128 tile, BK=32, 256 threads = 4 waves. Double-buffered LDS:
// one barrier per K-iter; prefetch of tile i+1 overlaps compute of tile i
// (the compiler's vmcnt(0) drain at __syncthreads provides completion).
// Grid is XCD-swizzled: all M-tiles of one N-column run on one XCD so the
// B-slice (256 KB) stays resident in that XCD's 4 MB L2.
// Requires gridDim.x % 8 == 0.
template <int BM, typename TOUT>
__global__ __launch_bounds__(256) void gemm_bt(
    const _Float16* __restrict__ A, const _Float16* __restrict__ B,
    const float* __restrict__ bias, TOUT* __restrict__ C,
    int M, int N, int K) {
  constexpr int WM = BM / 2;   // rows per wave
  constexpr int MI = WM / 16;  // mfma row-tiles per wave
  __shared__ _Float16 As[2][BM * 32];
  __shared__ _Float16 Bs[2][128 * 32];

  const int tid  = threadIdx.x;
  const int lane = tid & 63;
  const int wave = tid >> 6;
  const int l15  = lane & 15;
  const int quad = lane >> 4;

  // XCD swizzle: linear id -> (xcd, slot); xcd owns gridDim.x/8 N-columns.
  const int nlin = blockIdx.y * gridDim.x + blockIdx.x;
  const int xcd  = nlin & 7;
  const int slot = nlin >> 3;
  const int cpx  = gridDim.x >> 3;              // N-columns per XCD
  const int bx   = xcd * cpx + (slot % cpx);
  const int by   = slot / cpx;

  const int m0 = by * BM;
  const int n0 = bx * 128;
  const int wr = (wave >> 1) * WM;
  const int wc = (wave & 1) * 64;

  // staging: chunk c = issue*256 + tid ; row = c>>2, k-chunk = (c&3)*8
  const int srow = tid >> 2;
  const int skc  = (tid & 3) * 8;
  const _Float16* Ag0 = A + (size_t)(m0 + srow) * K + skc;
  const _Float16* Ag1 = A + (size_t)(m0 + 64 + srow) * K + skc;  // BM==128 only
  const _Float16* Bg0 = B + (size_t)(n0 + srow) * K + skc;
  const _Float16* Bg1 = B + (size_t)(n0 + 64 + srow) * K + skc;

  f32x4 acc[MI][4];
#pragma unroll
  for (int i = 0; i < MI; i++)
#pragma unroll
    for (int j = 0; j < 4; j++) acc[i][j] = f32x4{0.f, 0.f, 0.f, 0.f};

  auto prefetch = [&](int kt, int buf) {
    GLDS16(Ag0 + kt, &As[buf][tid * 8]);
    if constexpr (BM == 128) GLDS16(Ag1 + kt, &As[buf][(256 + tid) * 8]);
    GLDS16(Bg0 + kt, &Bs[buf][tid * 8]);
    GLDS16(Bg1 + kt, &Bs[buf][(256 + tid) * 8]);
  };
  auto compute = [&](int buf) {
    f16x8 af[MI], bf[4];
#pragma unroll
    for (int mi = 0; mi < MI; mi++)
      af[mi] = *reinterpret_cast<const f16x8*>(&As[buf][(wr + mi * 16 + l15) * 32 + quad * 8]);
#pragma unroll
    for (int ni = 0; ni < 4; ni++)
      bf[ni] = *reinterpret_cast<const f16x8*>(&Bs[buf][(wc + ni * 16 + l15) * 32 + quad * 8]);
#pragma unroll
    for (int mi = 0; mi < MI; mi++)
#pragma unroll
      for (int ni = 0; ni < 4; ni++)
        acc[mi][ni] = __builtin_amdgcn_mfma_f32_16x16x32_f16(af[mi], bf[ni], acc[mi][ni], 0, 0, 0);
  };

  const int NI = K >> 5;
  prefetch(0, 0);
  __syncthreads();                 // drains GLDS(0)
#pragma unroll 2
  for (int i = 0; i < NI - 1; ++i) {
    prefetch((i + 1) << 5, (i + 1) & 1);  // overlaps compute below
    compute(i & 1);
    __syncthreads();               // readers done + prefetch drained
  }
  compute((NI - 1) & 1);

  // epilogue: C/D layout row = quad*4 + r, col = l15
#pragma unroll
  for (int mi = 0; mi < MI; mi++) {
    const int row = m0 + wr + mi * 16 + quad * 4;
#pragma unroll
    for (int ni = 0; ni < 4; ni++) {
      const int col = n0 + wc + ni * 16 + l15;
      const float bv = bias ? bias[col] : 0.f;
#pragma unroll
      for (int r = 0; r < 4; r++) {
        float v = acc[mi][ni][r] + bv;
        C[(size_t)(row + r) * N + col] = (TOUT)v;
      }
    }
  }
}

// ---------------------------------------------------------------- windowed attention
#define T_LEN 1024
#define KSTR 72    // Kw row stride (elements), pad 64->72
#define VSTR 200   // Vt / P row stride, pad 192->200

__global__ __launch_bounds__(256) void attn_win(
    const _Float16* __restrict__ qkv, _Float16* __restrict__ o) {
  __shared__ _Float16 KP[192 * KSTR];  // K window [j][d]; later reused as P
  __shared__ _Float16 Vt[64 * VSTR];   // V window transposed [d][j]

  const int b  = blockIdx.x;
  const int qt = b & 15;
  const int h  = (b >> 4) & 15;
  const int n  = b >> 8;
  const int t0 = qt * 64;

  const int tid  = threadIdx.x;
  const int lane = tid & 63;
  const int wave = tid >> 6;
  const int l15  = lane & 15;
  const int quad = lane >> 4;

  const size_t rowstr = 3072;
  const _Float16* qbase = qkv + (size_t)n * T_LEN * rowstr + h * 64;
  const _Float16* kbase = qbase + 1024;
  const _Float16* vbase = qbase + 2048;

  // ---- Q fragments first (independent of LDS -> overlap staging latency)
  const _Float16* qrow = qbase + (size_t)(t0 + wave * 16 + l15) * rowstr;
  const f16x8 qf0 = *reinterpret_cast<const f16x8*>(qrow + quad * 8);
  const f16x8 qf1 = *reinterpret_cast<const f16x8*>(qrow + 32 + quad * 8);

  // ---- stage K window [192][64]: vector writes, 8 lanes per row
  for (int idx = tid; idx < 192 * 8; idx += 256) {
    const int j  = idx >> 3;
    const int d8 = (idx & 7) * 8;
    const int t  = t0 - 64 + j;
    f16x8 kv;
    if (t >= 0 && t < T_LEN) {
      kv = *reinterpret_cast<const f16x8*>(kbase + (size_t)t * rowstr + d8);
    } else {
      for (int i = 0; i < 8; i++) kv[i] = (_Float16)0.f;
    }
    *reinterpret_cast<f16x8*>(&KP[j * KSTR + d8]) = kv;
  }
  // ---- stage V^T [64][192]: consecutive lanes -> consecutive j (conflict-free)
  for (int it = 0; it < 6; it++) {
    const int item = it * 256 + tid;
    const int j    = (item & 63) + ((item >> 9) << 6);
    const int dgrp = (item >> 6) & 7;
    const int t = t0 - 64 + j;
    f16x8 vv;
    if (t >= 0 && t < T_LEN) {
      vv = *reinterpret_cast<const f16x8*>(vbase + (size_t)t * rowstr + dgrp * 8);
    } else {
      for (int i = 0; i < 8; i++) vv[i] = (_Float16)0.f;
    }
#pragma unroll
    for (int i = 0; i < 8; i++) Vt[(dgrp * 8 + i) * VSTR + j] = vv[i];
  }
  __syncthreads();

  // ---- S = Q K^T : 16x192 per wave = 12 tiles x 2 k-steps
  f32x4 accs[12];
#pragma unroll
  for (int jt = 0; jt < 12; jt++) accs[jt] = f32x4{0.f, 0.f, 0.f, 0.f};
#pragma unroll
  for (int jt = 0; jt < 12; jt++) {
    const f16x8 b0 = *reinterpret_cast<const f16x8*>(&KP[(jt * 16 + l15) * KSTR + quad * 8]);
    const f16x8 b1 = *reinterpret_cast<const f16x8*>(&KP[(jt * 16 + l15) * KSTR + 32 + quad * 8]);
    accs[jt] = __builtin_amdgcn_mfma_f32_16x16x32_f16(qf0, b0, accs[jt], 0, 0, 0);
    accs[jt] = __builtin_amdgcn_mfma_f32_16x16x32_f16(qf1, b1, accs[jt], 0, 0, 0);
  }
  __syncthreads();  // all waves done reading KP; it becomes P storage below

  // ---- mask + softmax (C layout: row q_local = quad*4+r, col j = jt*16+l15)
  float rmax[4] = {-1e30f, -1e30f, -1e30f, -1e30f};
#pragma unroll
  for (int jt = 0; jt < 12; jt++) {
    const int jcol = jt * 16 + l15;
    const int tabs = t0 - 64 + jcol;
#pragma unroll
    for (int r = 0; r < 4; r++) {
      const int q = wave * 16 + quad * 4 + r;
      const bool valid = (jcol >= q) && (jcol <= q + 128) && (tabs >= 0) && (tabs < T_LEN);
      const float s = valid ? accs[jt][r] * 0.125f : -1e30f;
      accs[jt][r] = s;
      rmax[r] = fmaxf(rmax[r], s);
    }
  }
#pragma unroll
  for (int r = 0; r < 4; r++)
#pragma unroll
    for (int m = 1; m < 16; m <<= 1) rmax[r] = fmaxf(rmax[r], __shfl_xor(rmax[r], m));

  float rsum[4] = {0.f, 0.f, 0.f, 0.f};
#pragma unroll
  for (int jt = 0; jt < 12; jt++)
#pragma unroll
    for (int r = 0; r < 4; r++) {
      const float p = __expf(accs[jt][r] - rmax[r]);
      accs[jt][r] = p;
      rsum[r] += p;
    }
#pragma unroll
  for (int r = 0; r < 4; r++)
#pragma unroll
    for (int m = 1; m < 16; m <<= 1) rsum[r] += __shfl_xor(rsum[r], m);

  // ---- write P (f16) to per-wave LDS region: C-layout -> A-layout transform
  _Float16* Pw = &KP[wave * 16 * VSTR];
#pragma unroll
  for (int jt = 0; jt < 12; jt++)
#pragma unroll
    for (int r = 0; r < 4; r++)
      Pw[(quad * 4 + r) * VSTR + jt * 16 + l15] = (_Float16)accs[jt][r];
  __syncthreads();

  // ---- O = P V : 16x64 per wave = 4 tiles x 6 k-steps
  f32x4 acco[4];
#pragma unroll
  for (int ni = 0; ni < 4; ni++) acco[ni] = f32x4{0.f, 0.f, 0.f, 0.f};
#pragma unroll
  for (int ks = 0; ks < 6; ks++) {
    const f16x8 pa = *reinterpret_cast<const f16x8*>(&Pw[l15 * VSTR + ks * 32 + quad * 8]);
#pragma unroll
    for (int ni = 0; ni < 4; ni++) {
      const f16x8 vb = *reinterpret_cast<const f16x8*>(&Vt[(ni * 16 + l15) * VSTR + ks * 32 + quad * 8]);
      acco[ni] = __builtin_amdgcn_mfma_f32_16x16x32_f16(pa, vb, acco[ni], 0, 0, 0);
    }
  }

  float rinv[4];
#pragma unroll
  for (int r = 0; r < 4; r++) rinv[r] = 1.f / rsum[r];

  _Float16* obase = o + (size_t)(n * T_LEN + t0 + wave * 16) * 1024 + h * 64;
#pragma unroll
  for (int ni = 0; ni < 4; ni++)
#pragma unroll
    for (int r = 0; r < 4; r++)
      obase[(size_t)(quad * 4 + r) * 1024 + ni * 16 + l15] = (_Float16)(acco[ni][r] * rinv[r]);
}

// ---------------------------------------------------------------- launch
extern "C" void kernel_launch(void* const* d_in, const int* in_sizes, int n_in,
                              void* d_out, int out_size, void* d_ws, size_t ws_size,
                              hipStream_t stream) {
  const float* x   = (const float*)d_in[0];
  const float* w_q = (const float*)d_in[1];
  const float* b_q = (const float*)d_in[2];
  const float* w_k = (const float*)d_in[3];
  const float* b_k = (const float*)d_in[4];
  const float* w_v = (const float*)d_in[5];
  const float* b_v = (const float*)d_in[6];
  const float* w_o = (const float*)d_in[7];
  const float* b_o = (const float*)d_in[8];
  float* out = (float*)d_out;

  char* ws = (char*)d_ws;
  _Float16* xh   = (_Float16*)(ws);                      // 2M el (4MB); reused as oh
  _Float16* wcat = (_Float16*)(ws + (4ull << 20));       // 3M el (6MB): [w_q; w_k; w_v]
  _Float16* woh  = (_Float16*)(ws + (10ull << 20));      // 1M el (2MB)
  _Float16* qkvh = (_Float16*)(ws + (12ull << 20));      // 6M el (12MB): (2048, 3072)
  _Float16* oh   = xh;                                   // alias: x dead after QKV gemm
  float*    bcat = (float*)(ws + (24ull << 20));         // 3072 f32

  // fused prep: 512K + 4*256K + 3*256 float4-units
  const int PREP_UNITS = 512 * 1024 + 4 * 256 * 1024 + 3 * 256;
  prep_kernel<<<(PREP_UNITS + 255) / 256, 256, 0, stream>>>(
      x, w_q, w_k, w_v, w_o, b_q, b_k, b_v, xh, wcat, woh, bcat);

  // fused QKV projection: (2048 x 1024) * (3072 x 1024)^T -> (2048 x 3072) f16
  gemm_bt<128, _Float16><<<dim3(24, 16), 256, 0, stream>>>(xh, wcat, bcat, qkvh, 2048, 3072, 1024);

  // windowed attention -> oh (2048 x 1024) f16
  attn_win<<<512, 256, 0, stream>>>(qkvh, oh);

  // output projection: (2048 x 1024) * (1024 x 1024)^T -> (2048 x 1024) f32
  gemm_bt<64, float><<<dim3(8, 32), 256, 0, stream>>>(oh, woh, b_o, out, 2048, 1024, 1024);
}

// Round 4
// 146.224 us; speedup vs baseline: 1.1210x; 1.0049x over previous
//
#include <hip/hip_runtime.h>
#include <hip/hip_fp16.h>
#include <cstdint>
#include <cstddef>

using f16x8  = _Float16 __attribute__((ext_vector_type(8)));
using f16x4  = _Float16 __attribute__((ext_vector_type(4)));
using f32x4  = float __attribute__((ext_vector_type(4)));
using f32x16 = float __attribute__((ext_vector_type(16)));

#define GLDS16(g, l) __builtin_amdgcn_global_load_lds(                        \
    (const __attribute__((address_space(1))) void*)(g),                       \
    (__attribute__((address_space(3))) void*)(l), 16, 0, 0)

// ---------------------------------------------------------------- fused prep
__device__ inline void cast4(const float* __restrict__ in,
                             _Float16* __restrict__ out, int i) {
  float4 v = reinterpret_cast<const float4*>(in)[i];
  f16x4 h;
  h[0] = (_Float16)v.x; h[1] = (_Float16)v.y;
  h[2] = (_Float16)v.z; h[3] = (_Float16)v.w;
  reinterpret_cast<f16x4*>(out)[i] = h;
}

__global__ void prep_kernel(const float* __restrict__ x,
                            const float* __restrict__ wq, const float* __restrict__ wk,
                            const float* __restrict__ wv, const float* __restrict__ wo,
                            const float* __restrict__ bq, const float* __restrict__ bk,
                            const float* __restrict__ bv,
                            _Float16* __restrict__ xh, _Float16* __restrict__ wcat,
                            _Float16* __restrict__ woh, float* __restrict__ bcat) {
  int i = blockIdx.x * blockDim.x + threadIdx.x;
  const int XU = 512 * 1024;  // x: 2M floats = 512K float4
  const int WU = 256 * 1024;  // each weight: 1M floats = 256K float4
  if (i < XU) { cast4(x, xh, i); return; }
  i -= XU;
  if (i < WU) { cast4(wq, wcat, i); return; }
  i -= WU;
  if (i < WU) { cast4(wk, wcat + 1024 * 1024, i); return; }
  i -= WU;
  if (i < WU) { cast4(wv, wcat + 2 * 1024 * 1024, i); return; }
  i -= WU;
  if (i < WU) { cast4(wo, woh, i); return; }
  i -= WU;
  if (i < 256) { reinterpret_cast<float4*>(bcat)[i] = reinterpret_cast<const float4*>(bq)[i]; return; }
  i -= 256;
  if (i < 256) { reinterpret_cast<float4*>(bcat + 1024)[i] = reinterpret_cast<const float4*>(bk)[i]; return; }
  i -= 256;
  if (i < 256) { reinterpret_cast<float4*>(bcat + 2048)[i] = reinterpret_cast<const float4*>(bv)[i]; return; }
}

// ---------------------------------------------------------------- GEMM  C = A * B^T + bias
// A: M x K (f16, row-major), B: N x K (f16, row-major), C: M x N (TOUT)
// BM x 128 tile, BK=32, 256 threads = 4 waves, single-buffered m97 K-loop
// (explicit dbuf measured neutral — R3). 32x32x16 MFMA: half the MFMA
// instructions of 16x16x32 at higher ceiling. __launch_bounds__(256,4)
// caps VGPR at 128 -> 4 blocks/CU co-resident (vs 3) to hide barrier drains.
// A-frag: m=lane&31, k=(lane>>5)*8+i ; B symmetric ;
// C/D: col=lane&31, row=(reg&3)+8*(reg>>2)+4*(lane>>5)   [m74/m101]
// Grid XCD-swizzled (gridDim.x % 8 == 0).
template <int BM, typename TOUT>
__global__ __launch_bounds__(256, 4) void gemm_bt(
    const _Float16* __restrict__ A, const _Float16* __restrict__ B,
    const float* __restrict__ bias, TOUT* __restrict__ C,
    int M, int N, int K) {
  constexpr int WM = BM / 2;   // rows per wave (64 or 32)
  constexpr int MI = WM / 32;  // 32-row mfma tiles per wave (2 or 1)
  __shared__ _Float16 As[BM * 32];
  __shared__ _Float16 Bs[128 * 32];

  const int tid  = threadIdx.x;
  const int lane = tid & 63;
  const int wave = tid >> 6;
  const int l31  = lane & 31;
  const int half = lane >> 5;

  // XCD swizzle: all M-tiles of one N-column land on one XCD.
  const int nlin = blockIdx.y * gridDim.x + blockIdx.x;
  const int xcd  = nlin & 7;
  const int slot = nlin >> 3;
  const int cpx  = gridDim.x >> 3;
  const int bx   = xcd * cpx + (slot % cpx);
  const int by   = slot / cpx;

  const int m0 = by * BM;
  const int n0 = bx * 128;
  const int wr = (wave >> 1) * WM;
  const int wc = (wave & 1) * 64;

  // staging: chunk c = issue*256 + tid ; row = c>>2, k-chunk = (c&3)*8
  const int srow = tid >> 2;
  const int skc  = (tid & 3) * 8;
  const _Float16* Ag0 = A + (size_t)(m0 + srow) * K + skc;
  const _Float16* Ag1 = A + (size_t)(m0 + 64 + srow) * K + skc;  // BM==128 only
  const _Float16* Bg0 = B + (size_t)(n0 + srow) * K + skc;
  const _Float16* Bg1 = B + (size_t)(n0 + 64 + srow) * K + skc;

  f32x16 acc[MI][2];
#pragma unroll
  for (int i = 0; i < MI; i++)
#pragma unroll
    for (int j = 0; j < 2; j++) acc[i][j] = (f32x16)0.0f;

  for (int kt = 0; kt < K; kt += 32) {
    __syncthreads();
    GLDS16(Ag0 + kt, &As[tid * 8]);
    if constexpr (BM == 128) GLDS16(Ag1 + kt, &As[(256 + tid) * 8]);
    GLDS16(Bg0 + kt, &Bs[tid * 8]);
    GLDS16(Bg1 + kt, &Bs[(256 + tid) * 8]);
    __syncthreads();

#pragma unroll
    for (int kh = 0; kh < 2; kh++) {
      f16x8 af[MI], bf[2];
#pragma unroll
      for (int mi = 0; mi < MI; mi++)
        af[mi] = *reinterpret_cast<const f16x8*>(
            &As[(wr + mi * 32 + l31) * 32 + kh * 16 + half * 8]);
#pragma unroll
      for (int ni = 0; ni < 2; ni++)
        bf[ni] = *reinterpret_cast<const f16x8*>(
            &Bs[(wc + ni * 32 + l31) * 32 + kh * 16 + half * 8]);
#pragma unroll
      for (int mi = 0; mi < MI; mi++)
#pragma unroll
        for (int ni = 0; ni < 2; ni++)
          acc[mi][ni] = __builtin_amdgcn_mfma_f32_32x32x16_f16(af[mi], bf[ni], acc[mi][ni], 0, 0, 0);
    }
  }

  // epilogue
#pragma unroll
  for (int mi = 0; mi < MI; mi++) {
    const int rbase = m0 + wr + mi * 32 + 4 * half;
#pragma unroll
    for (int ni = 0; ni < 2; ni++) {
      const int col = n0 + wc + ni * 32 + l31;
      const float bv = bias ? bias[col] : 0.f;
#pragma unroll
      for (int r = 0; r < 16; r++) {
        const int row = rbase + (r & 3) + 8 * (r >> 2);
        C[(size_t)row * N + col] = (TOUT)(acc[mi][ni][r] + bv);
      }
    }
  }
}

// ---------------------------------------------------------------- windowed attention
#define T_LEN 1024
#define KSTR 72    // Kw row stride (elements), pad 64->72
#define VSTR 200   // Vt / P row stride, pad 192->200

__global__ __launch_bounds__(256) void attn_win(
    const _Float16* __restrict__ qkv, _Float16* __restrict__ o) {
  __shared__ _Float16 KP[192 * KSTR];  // K window [j][d]; later reused as P
  __shared__ _Float16 Vt[64 * VSTR];   // V window transposed [d][j]

  const int b  = blockIdx.x;
  const int qt = b & 15;
  const int h  = (b >> 4) & 15;
  const int n  = b >> 8;
  const int t0 = qt * 64;

  const int tid  = threadIdx.x;
  const int lane = tid & 63;
  const int wave = tid >> 6;
  const int l15  = lane & 15;
  const int quad = lane >> 4;

  const size_t rowstr = 3072;
  const _Float16* qbase = qkv + (size_t)n * T_LEN * rowstr + h * 64;
  const _Float16* kbase = qbase + 1024;
  const _Float16* vbase = qbase + 2048;

  // ---- Q fragments first (overlap staging latency)
  const _Float16* qrow = qbase + (size_t)(t0 + wave * 16 + l15) * rowstr;
  const f16x8 qf0 = *reinterpret_cast<const f16x8*>(qrow + quad * 8);
  const f16x8 qf1 = *reinterpret_cast<const f16x8*>(qrow + 32 + quad * 8);

  // ---- stage K window [192][64]
  for (int idx = tid; idx < 192 * 8; idx += 256) {
    const int j  = idx >> 3;
    const int d8 = (idx & 7) * 8;
    const int t  = t0 - 64 + j;
    f16x8 kv;
    if (t >= 0 && t < T_LEN) {
      kv = *reinterpret_cast<const f16x8*>(kbase + (size_t)t * rowstr + d8);
    } else {
      for (int i = 0; i < 8; i++) kv[i] = (_Float16)0.f;
    }
    *reinterpret_cast<f16x8*>(&KP[j * KSTR + d8]) = kv;
  }
  // ---- stage V^T [64][192]: consecutive lanes -> consecutive j (conflict-free)
  for (int it = 0; it < 6; it++) {
    const int item = it * 256 + tid;
    const int j    = (item & 63) + ((item >> 9) << 6);
    const int dgrp = (item >> 6) & 7;
    const int t = t0 - 64 + j;
    f16x8 vv;
    if (t >= 0 && t < T_LEN) {
      vv = *reinterpret_cast<const f16x8*>(vbase + (size_t)t * rowstr + dgrp * 8);
    } else {
      for (int i = 0; i < 8; i++) vv[i] = (_Float16)0.f;
    }
#pragma unroll
    for (int i = 0; i < 8; i++) Vt[(dgrp * 8 + i) * VSTR + j] = vv[i];
  }
  __syncthreads();

  // ---- S = Q K^T : 16x192 per wave = 12 tiles x 2 k-steps
  f32x4 accs[12];
#pragma unroll
  for (int jt = 0; jt < 12; jt++) accs[jt] = f32x4{0.f, 0.f, 0.f, 0.f};
#pragma unroll
  for (int jt = 0; jt < 12; jt++) {
    const f16x8 b0 = *reinterpret_cast<const f16x8*>(&KP[(jt * 16 + l15) * KSTR + quad * 8]);
    const f16x8 b1 = *reinterpret_cast<const f16x8*>(&KP[(jt * 16 + l15) * KSTR + 32 + quad * 8]);
    accs[jt] = __builtin_amdgcn_mfma_f32_16x16x32_f16(qf0, b0, accs[jt], 0, 0, 0);
    accs[jt] = __builtin_amdgcn_mfma_f32_16x16x32_f16(qf1, b1, accs[jt], 0, 0, 0);
  }
  __syncthreads();  // all waves done reading KP; it becomes P storage below

  // ---- mask + softmax (C layout: row q_local = quad*4+r, col j = jt*16+l15)
  float rmax[4] = {-1e30f, -1e30f, -1e30f, -1e30f};
#pragma unroll
  for (int jt = 0; jt < 12; jt++) {
    const int jcol = jt * 16 + l15;
    const int tabs = t0 - 64 + jcol;
#pragma unroll
    for (int r = 0; r < 4; r++) {
      const int q = wave * 16 + quad * 4 + r;
      const bool valid = (jcol >= q) && (jcol <= q + 128) && (tabs >= 0) && (tabs < T_LEN);
      const float s = valid ? accs[jt][r] * 0.125f : -1e30f;
      accs[jt][r] = s;
      rmax[r] = fmaxf(rmax[r], s);
    }
  }
#pragma unroll
  for (int r = 0; r < 4; r++)
#pragma unroll
    for (int m = 1; m < 16; m <<= 1) rmax[r] = fmaxf(rmax[r], __shfl_xor(rmax[r], m));

  float rsum[4] = {0.f, 0.f, 0.f, 0.f};
#pragma unroll
  for (int jt = 0; jt < 12; jt++)
#pragma unroll
    for (int r = 0; r < 4; r++) {
      const float p = __expf(accs[jt][r] - rmax[r]);
      accs[jt][r] = p;
      rsum[r] += p;
    }
#pragma unroll
  for (int r = 0; r < 4; r++)
#pragma unroll
    for (int m = 1; m < 16; m <<= 1) rsum[r] += __shfl_xor(rsum[r], m);

  // ---- write P (f16) to per-wave LDS region: C-layout -> A-layout transform
  _Float16* Pw = &KP[wave * 16 * VSTR];
#pragma unroll
  for (int jt = 0; jt < 12; jt++)
#pragma unroll
    for (int r = 0; r < 4; r++)
      Pw[(quad * 4 + r) * VSTR + jt * 16 + l15] = (_Float16)accs[jt][r];
  __syncthreads();

  // ---- O = P V : 16x64 per wave = 4 tiles x 6 k-steps
  f32x4 acco[4];
#pragma unroll
  for (int ni = 0; ni < 4; ni++) acco[ni] = f32x4{0.f, 0.f, 0.f, 0.f};
#pragma unroll
  for (int ks = 0; ks < 6; ks++) {
    const f16x8 pa = *reinterpret_cast<const f16x8*>(&Pw[l15 * VSTR + ks * 32 + quad * 8]);
#pragma unroll
    for (int ni = 0; ni < 4; ni++) {
      const f16x8 vb = *reinterpret_cast<const f16x8*>(&Vt[(ni * 16 + l15) * VSTR + ks * 32 + quad * 8]);
      acco[ni] = __builtin_amdgcn_mfma_f32_16x16x32_f16(pa, vb, acco[ni], 0, 0, 0);
    }
  }

  float rinv[4];
#pragma unroll
  for (int r = 0; r < 4; r++) rinv[r] = 1.f / rsum[r];

  _Float16* obase = o + (size_t)(n * T_LEN + t0 + wave * 16) * 1024 + h * 64;
#pragma unroll
  for (int ni = 0; ni < 4; ni++)
#pragma unroll
    for (int r = 0; r < 4; r++)
      obase[(size_t)(quad * 4 + r) * 1024 + ni * 16 + l15] = (_Float16)(acco[ni][r] * rinv[r]);
}

// ---------------------------------------------------------------- launch
extern "C" void kernel_launch(void* const* d_in, const int* in_sizes, int n_in,
                              void* d_out, int out_size, void* d_ws, size_t ws_size,
                              hipStream_t stream) {
  const float* x   = (const float*)d_in[0];
  const float* w_q = (const float*)d_in[1];
  const float* b_q = (const float*)d_in[2];
  const float* w_k = (const float*)d_in[3];
  const float* b_k = (const float*)d_in[4];
  const float* w_v = (const float*)d_in[5];
  const float* b_v = (const float*)d_in[6];
  const float* w_o = (const float*)d_in[7];
  const float* b_o = (const float*)d_in[8];
  float* out = (float*)d_out;

  char* ws = (char*)d_ws;
  _Float16* xh   = (_Float16*)(ws);                      // 2M el (4MB); reused as oh
  _Float16* wcat = (_Float16*)(ws + (4ull << 20));       // 3M el (6MB): [w_q; w_k; w_v]
  _Float16* woh  = (_Float16*)(ws + (10ull << 20));      // 1M el (2MB)
  _Float16* qkvh = (_Float16*)(ws + (12ull << 20));      // 6M el (12MB): (2048, 3072)
  _Float16* oh   = xh;                                   // alias: x dead after QKV gemm
  float*    bcat = (float*)(ws + (24ull << 20));         // 3072 f32

  // fused prep: 512K + 4*256K + 3*256 float4-units
  const int PREP_UNITS = 512 * 1024 + 4 * 256 * 1024 + 3 * 256;
  prep_kernel<<<(PREP_UNITS + 255) / 256, 256, 0, stream>>>(
      x, w_q, w_k, w_v, w_o, b_q, b_k, b_v, xh, wcat, woh, bcat);

  // fused QKV projection: (2048 x 1024) * (3072 x 1024)^T -> (2048 x 3072) f16
  gemm_bt<128, _Float16><<<dim3(24, 16), 256, 0, stream>>>(xh, wcat, bcat, qkvh, 2048, 3072, 1024);

  // windowed attention -> oh (2048 x 1024) f16
  attn_win<<<512, 256, 0, stream>>>(qkvh, oh);

  // output projection: (2048 x 1024) * (1024 x 1024)^T -> (2048 x 1024) f32
  gemm_bt<64, float><<<dim3(8, 32), 256, 0, stream>>>(oh, woh, b_o, out, 2048, 1024, 1024);
}